// Round 2
// baseline (3495.812 us; speedup 1.0000x reference)
//
#include <hip/hip_runtime.h>
#include <hip/hip_bf16.h>
#include <stdint.h>

// ChimeraBlock (Mamba2-style) for MI355X — chunked, workspace-aware.
// Per chunk (CB images, R=CB*1024 rows):
//   cvt(u)->bf16 ; GEMM1 bf16 MFMA -> z(bf16, lives in d_out), xBC(bf16), dt(f32)
//   depthwise 3x3 conv + SiLU ; selective scan fwd/rev (f32 state) ; gate+RMSNorm
//   GEMM2 bf16 MFMA -> f32 d_out (overwrites the z scratch region).
// Aliasing: segA = u_bf then yf ; segC = xBC then yr ; segE = conv then yn.

#define D_MODEL 768
#define D_INNER 1536
#define NH 24
#define D_IN_PROJ 3424      // 2*1536 + 256 + 96
#define CONV_DIM 1792       // 1536 + 256
#define NDT 96
#define LSEQ 1024

typedef __bf16 bf16x8 __attribute__((ext_vector_type(8)));
typedef float f32x4 __attribute__((ext_vector_type(4)));

// ---------------- f32 -> bf16 convert (x4 vectorized) ----------------
__global__ void cvt_kernel(const float* __restrict__ src, __hip_bfloat16* __restrict__ dst, int n4) {
    int i = blockIdx.x * 256 + threadIdx.x;
    if (i < n4) {
        float4 v = ((const float4*)src)[i];
        __hip_bfloat162 lo, hi;
        lo.x = __float2bfloat16(v.x); lo.y = __float2bfloat16(v.y);
        hi.x = __float2bfloat16(v.z); hi.y = __float2bfloat16(v.w);
        ((__hip_bfloat162*)dst)[2*i]   = lo;
        ((__hip_bfloat162*)dst)[2*i+1] = hi;
    }
}

// ---------------- bf16 NT GEMM: C[m,n] = sum_k A[m,k] * Bt[n,k] ----------------
// 128x128 tile, BK=32, 256 threads (4 waves, each 64x64 via 4x4 of 16x16x32 MFMA).
__device__ __forceinline__ void gl_lds16(const __hip_bfloat16* g, __hip_bfloat16* l) {
    __builtin_amdgcn_global_load_lds(
        (const __attribute__((address_space(1))) void*)g,
        (__attribute__((address_space(3))) void*)l, 16, 0, 0);
}

// MODE 0: f32 out (OutF, width N).  MODE 1: split out -> Z(1536) | XBC(1792) | DT(96 f32)
template<int MODE>
__global__ __launch_bounds__(256) void gemm_bt(
    const __hip_bfloat16* __restrict__ A,   // M x K
    const __hip_bfloat16* __restrict__ Bt,  // N x K
    float* __restrict__ OutF,
    __hip_bfloat16* __restrict__ Z, __hip_bfloat16* __restrict__ XBC, float* __restrict__ DT,
    int M, int N, int K)
{
    __shared__ __hip_bfloat16 As[128*32];
    __shared__ __hip_bfloat16 Bs[128*32];
    const int tid  = threadIdx.x;
    const int wave = tid >> 6, lane = tid & 63;
    const int bm = blockIdx.x * 128, bn = blockIdx.y * 128;
    const int wm = (wave >> 1) * 64, wn = (wave & 1) * 64;
    f32x4 acc[4][4] = {};
    const int lrow = lane >> 2;        // 0..15 staging row within 16-row slab
    const int lcol = (lane & 3) * 8;   // 0,8,16,24 (bf16 elements)
    const int fr = lane & 15, fk = (lane >> 4) * 8;  // fragment row / k-chunk
    const int ktiles = K >> 5;
    for (int kt = 0; kt < ktiles; ++kt) {
        const int kofs = kt * 32;
        #pragma unroll
        for (int cc = 0; cc < 2; ++cc) {
            int r = (wave*2 + cc)*16 + lrow;
            gl_lds16(A + (size_t)(bm + r)*K + kofs + lcol, &As[r*32 + lcol]);
            int gn = bn + r; if (gn > N-1) gn = N-1;   // clamp partial N-tile
            gl_lds16(Bt + (size_t)gn*K + kofs + lcol, &Bs[r*32 + lcol]);
        }
        __syncthreads();
        bf16x8 af[4], bfr[4];
        #pragma unroll
        for (int i = 0; i < 4; ++i)
            af[i] = *reinterpret_cast<const bf16x8*>(&As[(wm + i*16 + fr)*32 + fk]);
        #pragma unroll
        for (int j = 0; j < 4; ++j)
            bfr[j] = *reinterpret_cast<const bf16x8*>(&Bs[(wn + j*16 + fr)*32 + fk]);
        #pragma unroll
        for (int i = 0; i < 4; ++i)
            #pragma unroll
            for (int j = 0; j < 4; ++j)
                acc[i][j] = __builtin_amdgcn_mfma_f32_16x16x32_bf16(af[i], bfr[j], acc[i][j], 0, 0, 0);
        __syncthreads();
    }
    // epilogue: C/D layout col = lane&15, row = (lane>>4)*4 + reg
    const int er = (lane >> 4) * 4;
    const int ec = lane & 15;
    #pragma unroll
    for (int i = 0; i < 4; ++i) {
        #pragma unroll
        for (int j = 0; j < 4; ++j) {
            #pragma unroll
            for (int r = 0; r < 4; ++r) {
                int row = bm + wm + i*16 + er + r;
                int col = bn + wn + j*16 + ec;
                if (col < N) {
                    float v = acc[i][j][r];
                    if (MODE == 0) {
                        OutF[(size_t)row*N + col] = v;
                    } else {
                        if (col < D_INNER)
                            Z[(size_t)row*D_INNER + col] = __float2bfloat16(v);
                        else if (col < D_INNER + CONV_DIM - D_INNER + 1536 + 256) { /* col < 3328 */
                            if (col < 3328)
                                XBC[(size_t)row*CONV_DIM + (col - D_INNER)] = __float2bfloat16(v);
                            else
                                DT[(size_t)row*NDT + (col - 3328)] = v;
                        }
                    }
                }
            }
        }
    }
}

// ---------------- depthwise 3x3 conv + bias + SiLU ----------------
__global__ __launch_bounds__(256) void conv_kernel(
    const __hip_bfloat16* __restrict__ xbc, // (R, 1792)
    const float* __restrict__ cw,           // (1792, 9)
    const float* __restrict__ cb,           // (1792)
    __hip_bfloat16* __restrict__ out)       // (R, 1792)
{
    size_t idx = (size_t)blockIdx.x * 256 + threadIdx.x;   // over R*1792
    int c = (int)(idx % CONV_DIM);
    size_t bp = idx / CONV_DIM;              // b_local*1024 + pix
    int pix = (int)(bp % LSEQ);
    int b = (int)(bp / LSEQ);
    int y = pix >> 5, x = pix & 31;
    float acc = cb[c];
    const float* w = cw + c*9;
    #pragma unroll
    for (int dy = -1; dy <= 1; ++dy) {
        int yy = y + dy; if (yy < 0 || yy > 31) continue;
        #pragma unroll
        for (int dx = -1; dx <= 1; ++dx) {
            int xx = x + dx; if (xx < 0 || xx > 31) continue;
            size_t r = ((size_t)b*LSEQ + yy*32 + xx)*CONV_DIM + c;
            acc += w[(dy+1)*3 + (dx+1)] * __bfloat162float(xbc[r]);
        }
    }
    float s = acc / (1.f + __expf(-acc));
    out[idx] = __float2bfloat16(s);
}

// ---------------- selective scan: block=(b,h,dir), 1 wave, both groups ----------------
__global__ __launch_bounds__(64, 1) void scan_kernel(
    const __hip_bfloat16* __restrict__ conv,  // (R, 1792): x | B(2x64) | C(2x64)
    const float* __restrict__ dtraw,          // (R, 96): [k=0..3][h=0..23]
    __hip_bfloat16* __restrict__ yf,          // (R, 1536)
    __hip_bfloat16* __restrict__ yr)          // (R, 1536)
{
    const int p = threadIdx.x;
    const int b = blockIdx.x, h = blockIdx.y, dir = blockIdx.z;
    const int k0 = dir ? 1 : 0, k1 = dir ? 3 : 2;
    __hip_bfloat16* yout = dir ? yr : yf;
    __shared__ __align__(16) float dtB[128];   // interleaved [g0,g1] per n
    __shared__ __align__(16) float Cs[128];
    float h0[64], h1[64];
    #pragma unroll
    for (int n = 0; n < 64; ++n) { h0[n] = 0.f; h1[n] = 0.f; }
    const size_t baseBL = (size_t)b * LSEQ;
    int tg0 = dir ? (LSEQ-1) : 0;
    size_t roff = (baseBL + tg0) * (size_t)CONV_DIM;
    float xp = __bfloat162float(conv[roff + h*64 + p]);
    float B0 = __bfloat162float(conv[roff + 1536 + p]);
    float B1 = __bfloat162float(conv[roff + 1600 + p]);
    float C0 = __bfloat162float(conv[roff + 1664 + p]);
    float C1 = __bfloat162float(conv[roff + 1728 + p]);
    float d0 = dtraw[(baseBL + tg0)*NDT + k0*24 + h];
    float d1 = dtraw[(baseBL + tg0)*NDT + k1*24 + h];
    for (int t = 0; t < LSEQ; ++t) {
        int tg = dir ? (LSEQ-1 - t) : t;
        // a = exp(-softplus(d)) = 1/(1+e^d) ; dt = log(1+e^d)
        float e0 = __expf(d0), e1 = __expf(d1);
        float dt0 = __logf(1.f + e0), dt1 = __logf(1.f + e1);
        float a0 = 1.f / (1.f + e0),  a1 = 1.f / (1.f + e1);
        float xcur = xp;
        __syncthreads();   // prior iteration's LDS reads done (WAR)
        dtB[2*p]   = dt0 * B0;  dtB[2*p+1] = dt1 * B1;
        Cs[2*p]    = C0;        Cs[2*p+1]  = C1;
        __syncthreads();   // writes visible (RAW)
        if (t < LSEQ-1) {  // prefetch next step
            int tg1 = dir ? (LSEQ-2 - t) : (t + 1);
            size_t r1 = (baseBL + tg1) * (size_t)CONV_DIM;
            xp = __bfloat162float(conv[r1 + h*64 + p]);
            B0 = __bfloat162float(conv[r1 + 1536 + p]);
            B1 = __bfloat162float(conv[r1 + 1600 + p]);
            C0 = __bfloat162float(conv[r1 + 1664 + p]);
            C1 = __bfloat162float(conv[r1 + 1728 + p]);
            d0 = dtraw[(baseBL + tg1)*NDT + k0*24 + h];
            d1 = dtraw[(baseBL + tg1)*NDT + k1*24 + h];
        }
        float y = 0.f;
        #pragma unroll
        for (int n2 = 0; n2 < 32; ++n2) {
            float4 q = *(float4*)&dtB[4*n2];   // {dtB0[n], dtB1[n], dtB0[n+1], dtB1[n+1]}
            float4 c = *(float4*)&Cs[4*n2];
            int n = 2*n2;
            h0[n]   = fmaf(a0, h0[n],   q.x * xcur);  y = fmaf(c.x, h0[n],   y);
            h1[n]   = fmaf(a1, h1[n],   q.y * xcur);  y = fmaf(c.y, h1[n],   y);
            h0[n+1] = fmaf(a0, h0[n+1], q.z * xcur);  y = fmaf(c.z, h0[n+1], y);
            h1[n+1] = fmaf(a1, h1[n+1], q.w * xcur);  y = fmaf(c.w, h1[n+1], y);
        }
        yout[(baseBL + tg)*(size_t)D_INNER + h*64 + p] = __float2bfloat16(y);
    }
}

// ---------------- gate (y * silu(z)) + RMSNorm + norm_w, bf16 out ----------------
__global__ __launch_bounds__(256) void gate_kernel(
    const __hip_bfloat16* __restrict__ yf, const __hip_bfloat16* __restrict__ yr,
    const __hip_bfloat16* __restrict__ z, const float* __restrict__ norm_w,
    __hip_bfloat16* __restrict__ yn)
{
    const int row = blockIdx.x, tid = threadIdx.x;
    const size_t ybase = (size_t)row * D_INNER;
    float yg[6]; float ss = 0.f;
    #pragma unroll
    for (int k = 0; k < 6; ++k) {
        int j = tid + k*256;
        float yv = __bfloat162float(yf[ybase+j]) + __bfloat162float(yr[ybase+j]);
        float zz = __bfloat162float(z[ybase+j]);
        float g  = yv * (zz / (1.f + __expf(-zz)));
        yg[k] = g; ss += g*g;
    }
    #pragma unroll
    for (int off = 32; off > 0; off >>= 1) ss += __shfl_down(ss, off, 64);
    __shared__ float red[4];
    if ((tid & 63) == 0) red[tid >> 6] = ss;
    __syncthreads();
    float total = red[0] + red[1] + red[2] + red[3];
    float rn = rsqrtf(total * (1.f/1536.f) + 1e-5f);
    #pragma unroll
    for (int k = 0; k < 6; ++k) {
        int j = tid + k*256;
        yn[ybase+j] = __float2bfloat16(yg[k] * rn * norm_w[j]);
    }
}

// ---------------- launch ----------------
extern "C" void kernel_launch(void* const* d_in, const int* in_sizes, int n_in,
                              void* d_out, int out_size, void* d_ws, size_t ws_size,
                              hipStream_t stream) {
    const float* u      = (const float*)d_in[0];   // (32,1024,768)
    const float* w_in   = (const float*)d_in[1];   // (3424,768)
    const float* conv_w = (const float*)d_in[2];   // (1792,1,3,3)
    const float* conv_b = (const float*)d_in[3];   // (1792)
    const float* norm_w = (const float*)d_in[4];   // (1536)
    const float* w_out  = (const float*)d_in[5];   // (768,1536)
    (void)in_sizes; (void)n_in; (void)out_size;

    char* ws = (char*)d_ws;
    const size_t nWin  = (size_t)D_IN_PROJ * D_MODEL;   // 2,629,632
    const size_t nWout = (size_t)D_MODEL * D_INNER;     // 1,179,648
    __hip_bfloat16* win_bf  = (__hip_bfloat16*)ws;                    // 5,259,264 B
    __hip_bfloat16* wout_bf = (__hip_bfloat16*)(ws + nWin*2);         // 2,359,296 B
    const size_t wbytes = nWin*2 + nWout*2;                           // 7,618,560 (256-aligned)
    char* arena = ws + wbytes;

    // per-row segment bytes: segA max(u 1536, yf 3072)=3072; segC max(xBC 3584, yr 3072)=3584;
    // segD dt 384; segE max(conv 3584, yn 3072)=3584  => 10624 B/row
    const size_t perRow = 10624;
    int CB = 32;
    while (CB > 1 && wbytes + perRow*(size_t)CB*1024 > ws_size) CB >>= 1;
    const int nchunks = 32 / CB;
    const size_t R = (size_t)CB * 1024;

    __hip_bfloat16* segA = (__hip_bfloat16*)arena;                 // u_bf, then yf
    char* pC = arena + R*3072;
    char* pD = pC + R*3584;
    char* pE = pD + R*384;
    __hip_bfloat16* xbc_bf  = (__hip_bfloat16*)pC;                 // then yr
    __hip_bfloat16* yr_bf   = (__hip_bfloat16*)pC;
    float*          dt_f32  = (float*)pD;
    __hip_bfloat16* conv_bf = (__hip_bfloat16*)pE;                 // then yn
    __hip_bfloat16* yn_bf   = (__hip_bfloat16*)pE;
    __hip_bfloat16* u_bf    = segA;
    __hip_bfloat16* yf_bf   = segA;

    // weight converts (once per call)
    cvt_kernel<<<(int)((nWin/4 + 255)/256), 256, 0, stream>>>(w_in, win_bf, (int)(nWin/4));
    cvt_kernel<<<(int)((nWout/4 + 255)/256), 256, 0, stream>>>(w_out, wout_bf, (int)(nWout/4));

    for (int c = 0; c < nchunks; ++c) {
        const float* u_c = u + (size_t)c * R * D_MODEL;
        __hip_bfloat16* z_bf = (__hip_bfloat16*)((char*)d_out + (size_t)c * R * 3072);
        float* out_c = (float*)d_out + (size_t)c * R * D_MODEL;

        const size_t nUc4 = R * D_MODEL / 4;
        cvt_kernel<<<(int)((nUc4 + 255)/256), 256, 0, stream>>>(u_c, u_bf, (int)nUc4);

        gemm_bt<1><<<dim3((int)(R/128), (D_IN_PROJ + 127)/128), 256, 0, stream>>>(
            u_bf, win_bf, nullptr, z_bf, xbc_bf, dt_f32, (int)R, D_IN_PROJ, D_MODEL);

        conv_kernel<<<(int)((R*CONV_DIM)/256), 256, 0, stream>>>(xbc_bf, conv_w, conv_b, conv_bf);

        scan_kernel<<<dim3(CB, NH, 2), 64, 0, stream>>>(conv_bf, dt_f32, yf_bf, yr_bf);

        gate_kernel<<<(int)R, 256, 0, stream>>>(yf_bf, yr_bf, z_bf, norm_w, yn_bf);

        gemm_bt<0><<<dim3((int)(R/128), D_MODEL/128), 256, 0, stream>>>(
            yn_bf, wout_bf, out_c, nullptr, nullptr, nullptr, (int)R, D_MODEL, D_INNER);
    }
}

// Round 3
// 2890.470 us; speedup vs baseline: 1.2094x; 1.2094x over previous
//
#include <hip/hip_runtime.h>
#include <hip/hip_bf16.h>
#include <stdint.h>

// ChimeraBlock (Mamba2-style) for MI355X — chunked, workspace-aware.
// Round 2 change: scan_kernel now uses 4 waves/block (states split across waves,
// per-t LDS partial-y reduction) to fix the 16%-occupancy latency stall.

#define D_MODEL 768
#define D_INNER 1536
#define NH 24
#define D_IN_PROJ 3424      // 2*1536 + 256 + 96
#define CONV_DIM 1792       // 1536 + 256
#define NDT 96
#define LSEQ 1024

typedef __bf16 bf16x8 __attribute__((ext_vector_type(8)));
typedef float f32x4 __attribute__((ext_vector_type(4)));

// ---------------- f32 -> bf16 convert (x4 vectorized) ----------------
__global__ void cvt_kernel(const float* __restrict__ src, __hip_bfloat16* __restrict__ dst, int n4) {
    int i = blockIdx.x * 256 + threadIdx.x;
    if (i < n4) {
        float4 v = ((const float4*)src)[i];
        __hip_bfloat162 lo, hi;
        lo.x = __float2bfloat16(v.x); lo.y = __float2bfloat16(v.y);
        hi.x = __float2bfloat16(v.z); hi.y = __float2bfloat16(v.w);
        ((__hip_bfloat162*)dst)[2*i]   = lo;
        ((__hip_bfloat162*)dst)[2*i+1] = hi;
    }
}

// ---------------- bf16 NT GEMM: C[m,n] = sum_k A[m,k] * Bt[n,k] ----------------
__device__ __forceinline__ void gl_lds16(const __hip_bfloat16* g, __hip_bfloat16* l) {
    __builtin_amdgcn_global_load_lds(
        (const __attribute__((address_space(1))) void*)g,
        (__attribute__((address_space(3))) void*)l, 16, 0, 0);
}

// MODE 0: f32 out (OutF, width N).  MODE 1: split out -> Z(1536) | XBC(1792) | DT(96 f32)
template<int MODE>
__global__ __launch_bounds__(256) void gemm_bt(
    const __hip_bfloat16* __restrict__ A,   // M x K
    const __hip_bfloat16* __restrict__ Bt,  // N x K
    float* __restrict__ OutF,
    __hip_bfloat16* __restrict__ Z, __hip_bfloat16* __restrict__ XBC, float* __restrict__ DT,
    int M, int N, int K)
{
    __shared__ __hip_bfloat16 As[128*32];
    __shared__ __hip_bfloat16 Bs[128*32];
    const int tid  = threadIdx.x;
    const int wave = tid >> 6, lane = tid & 63;
    const int bm = blockIdx.x * 128, bn = blockIdx.y * 128;
    const int wm = (wave >> 1) * 64, wn = (wave & 1) * 64;
    f32x4 acc[4][4] = {};
    const int lrow = lane >> 2;
    const int lcol = (lane & 3) * 8;
    const int fr = lane & 15, fk = (lane >> 4) * 8;
    const int ktiles = K >> 5;
    for (int kt = 0; kt < ktiles; ++kt) {
        const int kofs = kt * 32;
        #pragma unroll
        for (int cc = 0; cc < 2; ++cc) {
            int r = (wave*2 + cc)*16 + lrow;
            gl_lds16(A + (size_t)(bm + r)*K + kofs + lcol, &As[r*32 + lcol]);
            int gn = bn + r; if (gn > N-1) gn = N-1;   // clamp partial N-tile
            gl_lds16(Bt + (size_t)gn*K + kofs + lcol, &Bs[r*32 + lcol]);
        }
        __syncthreads();
        bf16x8 af[4], bfr[4];
        #pragma unroll
        for (int i = 0; i < 4; ++i)
            af[i] = *reinterpret_cast<const bf16x8*>(&As[(wm + i*16 + fr)*32 + fk]);
        #pragma unroll
        for (int j = 0; j < 4; ++j)
            bfr[j] = *reinterpret_cast<const bf16x8*>(&Bs[(wn + j*16 + fr)*32 + fk]);
        #pragma unroll
        for (int i = 0; i < 4; ++i)
            #pragma unroll
            for (int j = 0; j < 4; ++j)
                acc[i][j] = __builtin_amdgcn_mfma_f32_16x16x32_bf16(af[i], bfr[j], acc[i][j], 0, 0, 0);
        __syncthreads();
    }
    const int er = (lane >> 4) * 4;
    const int ec = lane & 15;
    #pragma unroll
    for (int i = 0; i < 4; ++i) {
        #pragma unroll
        for (int j = 0; j < 4; ++j) {
            #pragma unroll
            for (int r = 0; r < 4; ++r) {
                int row = bm + wm + i*16 + er + r;
                int col = bn + wn + j*16 + ec;
                if (col < N) {
                    float v = acc[i][j][r];
                    if (MODE == 0) {
                        OutF[(size_t)row*N + col] = v;
                    } else {
                        if (col < D_INNER)
                            Z[(size_t)row*D_INNER + col] = __float2bfloat16(v);
                        else if (col < 3328)
                            XBC[(size_t)row*CONV_DIM + (col - D_INNER)] = __float2bfloat16(v);
                        else
                            DT[(size_t)row*NDT + (col - 3328)] = v;
                    }
                }
            }
        }
    }
}

// ---------------- depthwise 3x3 conv + bias + SiLU ----------------
__global__ __launch_bounds__(256) void conv_kernel(
    const __hip_bfloat16* __restrict__ xbc, // (R, 1792)
    const float* __restrict__ cw,           // (1792, 9)
    const float* __restrict__ cb,           // (1792)
    __hip_bfloat16* __restrict__ out)       // (R, 1792)
{
    size_t idx = (size_t)blockIdx.x * 256 + threadIdx.x;   // over R*1792
    int c = (int)(idx % CONV_DIM);
    size_t bp = idx / CONV_DIM;
    int pix = (int)(bp % LSEQ);
    int b = (int)(bp / LSEQ);
    int y = pix >> 5, x = pix & 31;
    float acc = cb[c];
    const float* w = cw + c*9;
    #pragma unroll
    for (int dy = -1; dy <= 1; ++dy) {
        int yy = y + dy; if (yy < 0 || yy > 31) continue;
        #pragma unroll
        for (int dx = -1; dx <= 1; ++dx) {
            int xx = x + dx; if (xx < 0 || xx > 31) continue;
            size_t r = ((size_t)b*LSEQ + yy*32 + xx)*CONV_DIM + c;
            acc += w[(dy+1)*3 + (dx+1)] * __bfloat162float(xbc[r]);
        }
    }
    float s = acc / (1.f + __expf(-acc));
    out[idx] = __float2bfloat16(s);
}

// ---------------- selective scan: block=(b,h,dir), 4 waves ----------------
// 128 (group,n) states split 32/wave. Wave 0 produces the dtB/C broadcast and
// the final y (sum of per-wave partials via LDS). 2 barriers per t.
__global__ __launch_bounds__(256) void scan_kernel(
    const __hip_bfloat16* __restrict__ conv,  // (R, 1792): x | B(2x64) | C(2x64)
    const float* __restrict__ dtraw,          // (R, 96): [k=0..3][h=0..23]
    __hip_bfloat16* __restrict__ yf,          // (R, 1536)
    __hip_bfloat16* __restrict__ yr)          // (R, 1536)
{
    const int tid = threadIdx.x;
    const int w = tid >> 6, p = tid & 63;
    const int b = blockIdx.x, h = blockIdx.y, dir = blockIdx.z;
    const int k0 = dir ? 1 : 0, k1 = dir ? 3 : 2;
    __hip_bfloat16* yout = dir ? yr : yf;
    __shared__ __align__(16) float dtB[128];   // interleaved [g0,g1] per n
    __shared__ __align__(16) float Cs[128];
    __shared__ float ypart[192];               // partials from waves 1..3
    float h0[16], h1[16];
    #pragma unroll
    for (int n = 0; n < 16; ++n) { h0[n] = 0.f; h1[n] = 0.f; }
    const size_t baseBL = (size_t)b * LSEQ;
    int tg0 = dir ? (LSEQ-1) : 0;
    size_t roff = (baseBL + tg0) * (size_t)CONV_DIM;
    float xp = __bfloat162float(conv[roff + h*64 + p]);
    float B0 = 0.f, B1 = 0.f, C0 = 0.f, C1 = 0.f;
    if (w == 0) {
        B0 = __bfloat162float(conv[roff + 1536 + p]);
        B1 = __bfloat162float(conv[roff + 1600 + p]);
        C0 = __bfloat162float(conv[roff + 1664 + p]);
        C1 = __bfloat162float(conv[roff + 1728 + p]);
    }
    float d0 = dtraw[(baseBL + tg0)*NDT + k0*24 + h];
    float d1 = dtraw[(baseBL + tg0)*NDT + k1*24 + h];
    for (int t = 0; t < LSEQ; ++t) {
        int tg = dir ? (LSEQ-1 - t) : t;
        // a = exp(-softplus(d)) = 1/(1+e^d) ; dt = log(1+e^d)
        float e0 = __expf(d0), e1 = __expf(d1);
        float dt0 = __logf(1.f + e0), dt1 = __logf(1.f + e1);
        float a0 = 1.f / (1.f + e0),  a1 = 1.f / (1.f + e1);
        float xcur = xp;
        if (w == 0) {
            dtB[2*p]   = dt0 * B0;  dtB[2*p+1] = dt1 * B1;
            Cs[2*p]    = C0;        Cs[2*p+1]  = C1;
        }
        __syncthreads();   // dtB/Cs visible (RAW); also WAR for ypart reuse
        if (t < LSEQ-1) {  // prefetch next step
            int tg1 = dir ? (LSEQ-2 - t) : (t + 1);
            size_t r1 = (baseBL + tg1) * (size_t)CONV_DIM;
            xp = __bfloat162float(conv[r1 + h*64 + p]);
            if (w == 0) {
                B0 = __bfloat162float(conv[r1 + 1536 + p]);
                B1 = __bfloat162float(conv[r1 + 1600 + p]);
                C0 = __bfloat162float(conv[r1 + 1664 + p]);
                C1 = __bfloat162float(conv[r1 + 1728 + p]);
            }
            d0 = dtraw[(baseBL + tg1)*NDT + k0*24 + h];
            d1 = dtraw[(baseBL + tg1)*NDT + k1*24 + h];
        }
        float ya = 0.f, yb = 0.f, yc = 0.f, yd = 0.f;
        #pragma unroll
        for (int i = 0; i < 8; ++i) {
            int idx = w*8 + i;
            float4 q = *(float4*)&dtB[4*idx];
            float4 c = *(float4*)&Cs[4*idx];
            int n = 2*i;
            h0[n]   = fmaf(a0, h0[n],   q.x * xcur);  ya = fmaf(c.x, h0[n],   ya);
            h1[n]   = fmaf(a1, h1[n],   q.y * xcur);  yb = fmaf(c.y, h1[n],   yb);
            h0[n+1] = fmaf(a0, h0[n+1], q.z * xcur);  yc = fmaf(c.z, h0[n+1], yc);
            h1[n+1] = fmaf(a1, h1[n+1], q.w * xcur);  yd = fmaf(c.w, h1[n+1], yd);
        }
        float y = (ya + yb) + (yc + yd);
        if (w) ypart[(w-1)*64 + p] = y;
        __syncthreads();   // ypart visible; also WAR for dtB/Cs next write
        if (w == 0) {
            y += ypart[p] + ypart[64 + p] + ypart[128 + p];
            yout[(baseBL + tg)*(size_t)D_INNER + h*64 + p] = __float2bfloat16(y);
        }
    }
}

// ---------------- gate (y * silu(z)) + RMSNorm + norm_w, bf16 out ----------------
__global__ __launch_bounds__(256) void gate_kernel(
    const __hip_bfloat16* __restrict__ yf, const __hip_bfloat16* __restrict__ yr,
    const __hip_bfloat16* __restrict__ z, const float* __restrict__ norm_w,
    __hip_bfloat16* __restrict__ yn)
{
    const int row = blockIdx.x, tid = threadIdx.x;
    const size_t ybase = (size_t)row * D_INNER;
    float yg[6]; float ss = 0.f;
    #pragma unroll
    for (int k = 0; k < 6; ++k) {
        int j = tid + k*256;
        float yv = __bfloat162float(yf[ybase+j]) + __bfloat162float(yr[ybase+j]);
        float zz = __bfloat162float(z[ybase+j]);
        float g  = yv * (zz / (1.f + __expf(-zz)));
        yg[k] = g; ss += g*g;
    }
    #pragma unroll
    for (int off = 32; off > 0; off >>= 1) ss += __shfl_down(ss, off, 64);
    __shared__ float red[4];
    if ((tid & 63) == 0) red[tid >> 6] = ss;
    __syncthreads();
    float total = red[0] + red[1] + red[2] + red[3];
    float rn = rsqrtf(total * (1.f/1536.f) + 1e-5f);
    #pragma unroll
    for (int k = 0; k < 6; ++k) {
        int j = tid + k*256;
        yn[ybase+j] = __float2bfloat16(yg[k] * rn * norm_w[j]);
    }
}

// ---------------- launch ----------------
extern "C" void kernel_launch(void* const* d_in, const int* in_sizes, int n_in,
                              void* d_out, int out_size, void* d_ws, size_t ws_size,
                              hipStream_t stream) {
    const float* u      = (const float*)d_in[0];   // (32,1024,768)
    const float* w_in   = (const float*)d_in[1];   // (3424,768)
    const float* conv_w = (const float*)d_in[2];   // (1792,1,3,3)
    const float* conv_b = (const float*)d_in[3];   // (1792)
    const float* norm_w = (const float*)d_in[4];   // (1536)
    const float* w_out  = (const float*)d_in[5];   // (768,1536)
    (void)in_sizes; (void)n_in; (void)out_size;

    char* ws = (char*)d_ws;
    const size_t nWin  = (size_t)D_IN_PROJ * D_MODEL;
    const size_t nWout = (size_t)D_MODEL * D_INNER;
    __hip_bfloat16* win_bf  = (__hip_bfloat16*)ws;
    __hip_bfloat16* wout_bf = (__hip_bfloat16*)(ws + nWin*2);
    const size_t wbytes = nWin*2 + nWout*2;
    char* arena = ws + wbytes;

    // per-row bytes: segA max(u 1536, yf 3072)=3072; segC max(xBC 3584, yr 3072)=3584;
    // segD dt 384; segE max(conv 3584, yn 3072)=3584  => 10624 B/row
    const size_t perRow = 10624;
    int CB = 32;
    while (CB > 1 && wbytes + perRow*(size_t)CB*1024 > ws_size) CB >>= 1;
    const int nchunks = 32 / CB;
    const size_t R = (size_t)CB * 1024;

    __hip_bfloat16* segA = (__hip_bfloat16*)arena;                 // u_bf, then yf
    char* pC = arena + R*3072;
    char* pD = pC + R*3584;
    char* pE = pD + R*384;
    __hip_bfloat16* xbc_bf  = (__hip_bfloat16*)pC;                 // then yr
    __hip_bfloat16* yr_bf   = (__hip_bfloat16*)pC;
    float*          dt_f32  = (float*)pD;
    __hip_bfloat16* conv_bf = (__hip_bfloat16*)pE;                 // then yn
    __hip_bfloat16* yn_bf   = (__hip_bfloat16*)pE;
    __hip_bfloat16* u_bf    = segA;
    __hip_bfloat16* yf_bf   = segA;

    cvt_kernel<<<(int)((nWin/4 + 255)/256), 256, 0, stream>>>(w_in, win_bf, (int)(nWin/4));
    cvt_kernel<<<(int)((nWout/4 + 255)/256), 256, 0, stream>>>(w_out, wout_bf, (int)(nWout/4));

    for (int c = 0; c < nchunks; ++c) {
        const float* u_c = u + (size_t)c * R * D_MODEL;
        __hip_bfloat16* z_bf = (__hip_bfloat16*)((char*)d_out + (size_t)c * R * 3072);
        float* out_c = (float*)d_out + (size_t)c * R * D_MODEL;

        const size_t nUc4 = R * D_MODEL / 4;
        cvt_kernel<<<(int)((nUc4 + 255)/256), 256, 0, stream>>>(u_c, u_bf, (int)nUc4);

        gemm_bt<1><<<dim3((int)(R/128), (D_IN_PROJ + 127)/128), 256, 0, stream>>>(
            u_bf, win_bf, nullptr, z_bf, xbc_bf, dt_f32, (int)R, D_IN_PROJ, D_MODEL);

        conv_kernel<<<(int)((R*CONV_DIM)/256), 256, 0, stream>>>(xbc_bf, conv_w, conv_b, conv_bf);

        scan_kernel<<<dim3(CB, NH, 2), 256, 0, stream>>>(conv_bf, dt_f32, yf_bf, yr_bf);

        gate_kernel<<<(int)R, 256, 0, stream>>>(yf_bf, yr_bf, z_bf, norm_w, yn_bf);

        gemm_bt<0><<<dim3((int)(R/128), D_MODEL/128), 256, 0, stream>>>(
            yn_bf, wout_bf, out_c, nullptr, nullptr, nullptr, (int)R, D_MODEL, D_INNER);
    }
}

// Round 4
// 1829.602 us; speedup vs baseline: 1.9107x; 1.5798x over previous
//
#include <hip/hip_runtime.h>
#include <hip/hip_bf16.h>
#include <stdint.h>

// ChimeraBlock (Mamba2-style) for MI355X.
// Round 4: selective scan rewritten as chunked SSD on MFMA (chunk Q=64):
//   G = C B^T (MFMA) ; G' = mask(G) ; Y = G' X + (e^-S C) H ; H = e^-S63 H + (wB)^T X
// One block per (b,h,dir), 4 waves, H state in VGPRs across 16 sequential chunks.

#define D_MODEL 768
#define D_INNER 1536
#define NH 24
#define D_IN_PROJ 3424      // 2*1536 + 256 + 96
#define CONV_DIM 1792       // 1536 + 256
#define NDT 96
#define LSEQ 1024

typedef __bf16 bf16x8 __attribute__((ext_vector_type(8)));
typedef float f32x4 __attribute__((ext_vector_type(4)));

// ---------------- f32 -> bf16 convert (x4 vectorized) ----------------
__global__ void cvt_kernel(const float* __restrict__ src, __hip_bfloat16* __restrict__ dst, int n4) {
    int i = blockIdx.x * 256 + threadIdx.x;
    if (i < n4) {
        float4 v = ((const float4*)src)[i];
        __hip_bfloat162 lo, hi;
        lo.x = __float2bfloat16(v.x); lo.y = __float2bfloat16(v.y);
        hi.x = __float2bfloat16(v.z); hi.y = __float2bfloat16(v.w);
        ((__hip_bfloat162*)dst)[2*i]   = lo;
        ((__hip_bfloat162*)dst)[2*i+1] = hi;
    }
}

// ---------------- bf16 NT GEMM: C[m,n] = sum_k A[m,k] * Bt[n,k] ----------------
__device__ __forceinline__ void gl_lds16(const __hip_bfloat16* g, __hip_bfloat16* l) {
    __builtin_amdgcn_global_load_lds(
        (const __attribute__((address_space(1))) void*)g,
        (__attribute__((address_space(3))) void*)l, 16, 0, 0);
}

// MODE 0: f32 out (OutF, width N).  MODE 1: split out -> Z(1536) | XBC(1792) | DT(96 f32)
template<int MODE>
__global__ __launch_bounds__(256) void gemm_bt(
    const __hip_bfloat16* __restrict__ A,   // M x K
    const __hip_bfloat16* __restrict__ Bt,  // N x K
    float* __restrict__ OutF,
    __hip_bfloat16* __restrict__ Z, __hip_bfloat16* __restrict__ XBC, float* __restrict__ DT,
    int M, int N, int K)
{
    __shared__ __hip_bfloat16 As[128*32];
    __shared__ __hip_bfloat16 Bs[128*32];
    const int tid  = threadIdx.x;
    const int wave = tid >> 6, lane = tid & 63;
    const int bm = blockIdx.x * 128, bn = blockIdx.y * 128;
    const int wm = (wave >> 1) * 64, wn = (wave & 1) * 64;
    f32x4 acc[4][4] = {};
    const int lrow = lane >> 2;
    const int lcol = (lane & 3) * 8;
    const int fr = lane & 15, fk = (lane >> 4) * 8;
    const int ktiles = K >> 5;
    for (int kt = 0; kt < ktiles; ++kt) {
        const int kofs = kt * 32;
        #pragma unroll
        for (int cc = 0; cc < 2; ++cc) {
            int r = (wave*2 + cc)*16 + lrow;
            gl_lds16(A + (size_t)(bm + r)*K + kofs + lcol, &As[r*32 + lcol]);
            int gn = bn + r; if (gn > N-1) gn = N-1;
            gl_lds16(Bt + (size_t)gn*K + kofs + lcol, &Bs[r*32 + lcol]);
        }
        __syncthreads();
        bf16x8 af[4], bfr[4];
        #pragma unroll
        for (int i = 0; i < 4; ++i)
            af[i] = *reinterpret_cast<const bf16x8*>(&As[(wm + i*16 + fr)*32 + fk]);
        #pragma unroll
        for (int j = 0; j < 4; ++j)
            bfr[j] = *reinterpret_cast<const bf16x8*>(&Bs[(wn + j*16 + fr)*32 + fk]);
        #pragma unroll
        for (int i = 0; i < 4; ++i)
            #pragma unroll
            for (int j = 0; j < 4; ++j)
                acc[i][j] = __builtin_amdgcn_mfma_f32_16x16x32_bf16(af[i], bfr[j], acc[i][j], 0, 0, 0);
        __syncthreads();
    }
    const int er = (lane >> 4) * 4;
    const int ec = lane & 15;
    #pragma unroll
    for (int i = 0; i < 4; ++i) {
        #pragma unroll
        for (int j = 0; j < 4; ++j) {
            #pragma unroll
            for (int r = 0; r < 4; ++r) {
                int row = bm + wm + i*16 + er + r;
                int col = bn + wn + j*16 + ec;
                if (col < N) {
                    float v = acc[i][j][r];
                    if (MODE == 0) {
                        OutF[(size_t)row*N + col] = v;
                    } else {
                        if (col < D_INNER)
                            Z[(size_t)row*D_INNER + col] = __float2bfloat16(v);
                        else if (col < 3328)
                            XBC[(size_t)row*CONV_DIM + (col - D_INNER)] = __float2bfloat16(v);
                        else
                            DT[(size_t)row*NDT + (col - 3328)] = v;
                    }
                }
            }
        }
    }
}

// ---------------- depthwise 3x3 conv + bias + SiLU ----------------
__global__ __launch_bounds__(256) void conv_kernel(
    const __hip_bfloat16* __restrict__ xbc, // (R, 1792)
    const float* __restrict__ cw,           // (1792, 9)
    const float* __restrict__ cb,           // (1792)
    __hip_bfloat16* __restrict__ out)       // (R, 1792)
{
    size_t idx = (size_t)blockIdx.x * 256 + threadIdx.x;
    int c = (int)(idx % CONV_DIM);
    size_t bp = idx / CONV_DIM;
    int pix = (int)(bp % LSEQ);
    int b = (int)(bp / LSEQ);
    int y = pix >> 5, x = pix & 31;
    float acc = cb[c];
    const float* w = cw + c*9;
    #pragma unroll
    for (int dy = -1; dy <= 1; ++dy) {
        int yy = y + dy; if (yy < 0 || yy > 31) continue;
        #pragma unroll
        for (int dx = -1; dx <= 1; ++dx) {
            int xx = x + dx; if (xx < 0 || xx > 31) continue;
            size_t r = ((size_t)b*LSEQ + yy*32 + xx)*CONV_DIM + c;
            acc += w[(dy+1)*3 + (dx+1)] * __bfloat162float(xbc[r]);
        }
    }
    float s = acc / (1.f + __expf(-acc));
    out[idx] = __float2bfloat16(s);
}

// ---------------- chunked SSD scan on MFMA ----------------
// Block = (b, h, dir), 256 threads (4 waves, wave w owns 16-row m-slab).
// LDS arrays padded to stride 72 (144 B rows: 16B-aligned, bank-spread).
#define PADW 72
__device__ __forceinline__ bf16x8 ldfrag(const __bf16* base, int row, int k) {
    return *reinterpret_cast<const bf16x8*>(base + row*PADW + k);
}
__device__ __forceinline__ f32x4 mfma16(bf16x8 a, bf16x8 b, f32x4 c) {
    return __builtin_amdgcn_mfma_f32_16x16x32_bf16(a, b, c, 0, 0, 0);
}

__global__ __launch_bounds__(256) void scan_ssd(
    const __bf16* __restrict__ conv,   // (R, 1792): x | B(2x64) | C(2x64)
    const float* __restrict__ dtraw,   // (R, 96): [k][h], k = 2g + dir
    __bf16* __restrict__ yf,           // (R, 1536)
    __bf16* __restrict__ yr)           // (R, 1536)
{
    const int tid = threadIdx.x;
    const int w = tid >> 6, lane = tid & 63;
    const int b = blockIdx.x, h = blockIdx.y, dir = blockIdx.z;
    __bf16* yout = dir ? yr : yf;
    const size_t base = (size_t)b * LSEQ;

    __shared__ __align__(16) __bf16 XT[64*PADW];  // X^T: [p][tau]
    __shared__ __align__(16) __bf16 Bs[64*PADW];  // B:   [tau(s)][n]
    __shared__ __align__(16) __bf16 Cs[64*PADW];  // C:   [tau][n]
    __shared__ __align__(16) __bf16 Gs[64*PADW];  // G':  [tau][s]
    __shared__ __align__(16) __bf16 Ts[64*PADW];  // (wB)^T: [n][s]
    __shared__ __align__(16) __bf16 HT[64*PADW];  // H^T: [p][n]
    __shared__ float Sarr[2][64], Dtar[2][64], Warr[2][64], Earr[2][64];

    f32x4 Hst[2][4] = {};                  // state H[n][p]: n-slab = wave, 2 groups

    const int srow = tid >> 2;             // staging: physical row offset 0..63
    const int scol = (tid & 3) * 16;       // staging: 16-element column group
    const int fr = lane & 15, fkq = (lane >> 4) * 8;   // frag row / k base
    const int er = (lane >> 4) * 4, ec = lane & 15;    // C/D row base / col

    for (int c = 0; c < 16; ++c) {
        const int rA = dir ? (LSEQ - (c+1)*64) : c*64;   // physical start row in image
        __syncthreads();   // (z) guard all LDS overwrites vs prev chunk reads
        {   // stage X^T (scatter-transpose) ; compute S arrays (waves 0,1)
            const int q = srow; const int tau = dir ? 63 - q : q;
            const __bf16* src = conv + (base + rA + q) * (size_t)CONV_DIM + h*64 + scol;
            bf16x8 v0 = *(const bf16x8*)(src);
            bf16x8 v1 = *(const bf16x8*)(src + 8);
            #pragma unroll
            for (int i = 0; i < 8; ++i) XT[(scol+i)*PADW + tau] = v0[i];
            #pragma unroll
            for (int i = 0; i < 8; ++i) XT[(scol+8+i)*PADW + tau] = v1[i];
            if (tid < 128) {
                const int g = tid >> 6;
                const int t2 = lane;                       // scan position
                const int k = 2*g + dir;
                const int rowg = rA + (dir ? 63 - t2 : t2);
                float draw = dtraw[(base + rowg)*NDT + k*24 + h];
                float e = __expf(draw);
                float dts = __logf(1.f + e);               // softplus
                float s = dts;
                #pragma unroll
                for (int off = 1; off < 64; off <<= 1) {   // inclusive prefix sum
                    float v = __shfl_up(s, off, 64);
                    if (lane >= off) s += v;
                }
                float stot = __shfl(s, 63, 64);
                Sarr[g][t2] = s;
                Dtar[g][t2] = dts;
                Warr[g][t2] = __expf(s - stot) * dts;
                Earr[g][t2] = __expf(-s);
            }
        }
        __syncthreads();   // (a)
        f32x4 Yacc[4] = {};
        #pragma unroll 1
        for (int g = 0; g < 2; ++g) {
            if (g == 1) __syncthreads();   // WAR: Bs/Cs/HT/Ts overwrite vs g0 reads
            {   // stage Bs, Cs for this group
                const int q = srow; const int tau = dir ? 63 - q : q;
                const __bf16* src = conv + (base + rA + q) * (size_t)CONV_DIM;
                bf16x8 bv0 = *(const bf16x8*)(src + 1536 + g*64 + scol);
                bf16x8 bv1 = *(const bf16x8*)(src + 1536 + g*64 + scol + 8);
                *(bf16x8*)&Bs[tau*PADW + scol]     = bv0;
                *(bf16x8*)&Bs[tau*PADW + scol + 8] = bv1;
                bf16x8 cv0 = *(const bf16x8*)(src + 1664 + g*64 + scol);
                bf16x8 cv1 = *(const bf16x8*)(src + 1664 + g*64 + scol + 8);
                *(bf16x8*)&Cs[tau*PADW + scol]     = cv0;
                *(bf16x8*)&Cs[tau*PADW + scol + 8] = cv1;
            }
            // write H^T (h_init, unscaled) from regs
            #pragma unroll
            for (int t4 = 0; t4 < 4; ++t4)
                #pragma unroll
                for (int rr = 0; rr < 4; ++rr) {
                    int n = w*16 + er + rr;
                    int p = t4*16 + ec;
                    HT[p*PADW + n] = (__bf16)Hst[g][t4][rr];
                }
            __syncthreads();   // (b)
            // G = C B^T  (K = n = 64); keep C frags for Y-inter
            f32x4 Gacc[4] = {};
            bf16x8 cfr0 = ldfrag(Cs, w*16 + fr, fkq);
            bf16x8 cfr1 = ldfrag(Cs, w*16 + fr, 32 + fkq);
            #pragma unroll
            for (int s4 = 0; s4 < 4; ++s4) {
                bf16x8 bb0 = ldfrag(Bs, s4*16 + fr, fkq);
                bf16x8 bb1 = ldfrag(Bs, s4*16 + fr, 32 + fkq);
                Gacc[s4] = mfma16(cfr0, bb0, Gacc[s4]);
                Gacc[s4] = mfma16(cfr1, bb1, Gacc[s4]);
            }
            // scale H regs by chunk decay
            float e63 = Earr[g][63];
            #pragma unroll
            for (int t4 = 0; t4 < 4; ++t4)
                #pragma unroll
                for (int rr = 0; rr < 4; ++rr) Hst[g][t4][rr] *= e63;
            // mask G -> Gs (bf16): M[tau,s] = exp(S_s - S_tau)*dt_s for tau>=s
            #pragma unroll
            for (int s4 = 0; s4 < 4; ++s4) {
                int s = s4*16 + ec;
                float Ss = Sarr[g][s], dts = Dtar[g][s];
                #pragma unroll
                for (int rr = 0; rr < 4; ++rr) {
                    int tau = w*16 + er + rr;
                    float m = (tau >= s) ? __expf(Ss - Sarr[g][tau]) * dts : 0.f;
                    Gs[tau*PADW + s] = (__bf16)(Gacc[s4][rr] * m);
                }
            }
            // Ts = (w_s * B_s)^T : [n][s]
            {
                const int s = srow;
                float ws = Warr[g][s];
                bf16x8 b0 = *(const bf16x8*)&Bs[s*PADW + scol];
                bf16x8 b1 = *(const bf16x8*)&Bs[s*PADW + scol + 8];
                #pragma unroll
                for (int i = 0; i < 8; ++i) Ts[(scol+i)*PADW + s]   = (__bf16)((float)b0[i] * ws);
                #pragma unroll
                for (int i = 0; i < 8; ++i) Ts[(scol+8+i)*PADW + s] = (__bf16)((float)b1[i] * ws);
            }
            __syncthreads();   // (c)
            // Y += G' X + (E*C) H ; H += (wB)^T X
            bf16x8 ga0 = ldfrag(Gs, w*16 + fr, fkq);
            bf16x8 ga1 = ldfrag(Gs, w*16 + fr, 32 + fkq);
            float esc = Earr[g][w*16 + fr];
            bf16x8 ca0, ca1;
            #pragma unroll
            for (int i = 0; i < 8; ++i) { ca0[i] = (__bf16)((float)cfr0[i] * esc);
                                          ca1[i] = (__bf16)((float)cfr1[i] * esc); }
            bf16x8 ta0 = ldfrag(Ts, w*16 + fr, fkq);
            bf16x8 ta1 = ldfrag(Ts, w*16 + fr, 32 + fkq);
            #pragma unroll
            for (int p4 = 0; p4 < 4; ++p4) {
                bf16x8 x0 = ldfrag(XT, p4*16 + fr, fkq);
                bf16x8 x1 = ldfrag(XT, p4*16 + fr, 32 + fkq);
                Yacc[p4] = mfma16(ga0, x0, Yacc[p4]);
                Yacc[p4] = mfma16(ga1, x1, Yacc[p4]);
                bf16x8 h0 = ldfrag(HT, p4*16 + fr, fkq);
                bf16x8 h1 = ldfrag(HT, p4*16 + fr, 32 + fkq);
                Yacc[p4] = mfma16(ca0, h0, Yacc[p4]);
                Yacc[p4] = mfma16(ca1, h1, Yacc[p4]);
                Hst[g][p4] = mfma16(ta0, x0, Hst[g][p4]);
                Hst[g][p4] = mfma16(ta1, x1, Hst[g][p4]);
            }
        }
        // write Y chunk (sum of both groups)
        #pragma unroll
        for (int p4 = 0; p4 < 4; ++p4)
            #pragma unroll
            for (int rr = 0; rr < 4; ++rr) {
                int tau = w*16 + er + rr;
                int rowp = rA + (dir ? 63 - tau : tau);
                yout[(base + rowp)*(size_t)D_INNER + h*64 + p4*16 + ec] = (__bf16)Yacc[p4][rr];
            }
    }
}

// ---------------- gate (y * silu(z)) + RMSNorm + norm_w, bf16 out ----------------
__global__ __launch_bounds__(256) void gate_kernel(
    const __hip_bfloat16* __restrict__ yf, const __hip_bfloat16* __restrict__ yr,
    const __hip_bfloat16* __restrict__ z, const float* __restrict__ norm_w,
    __hip_bfloat16* __restrict__ yn)
{
    const int row = blockIdx.x, tid = threadIdx.x;
    const size_t ybase = (size_t)row * D_INNER;
    float yg[6]; float ss = 0.f;
    #pragma unroll
    for (int k = 0; k < 6; ++k) {
        int j = tid + k*256;
        float yv = __bfloat162float(yf[ybase+j]) + __bfloat162float(yr[ybase+j]);
        float zz = __bfloat162float(z[ybase+j]);
        float g  = yv * (zz / (1.f + __expf(-zz)));
        yg[k] = g; ss += g*g;
    }
    #pragma unroll
    for (int off = 32; off > 0; off >>= 1) ss += __shfl_down(ss, off, 64);
    __shared__ float red[4];
    if ((tid & 63) == 0) red[tid >> 6] = ss;
    __syncthreads();
    float total = red[0] + red[1] + red[2] + red[3];
    float rn = rsqrtf(total * (1.f/1536.f) + 1e-5f);
    #pragma unroll
    for (int k = 0; k < 6; ++k) {
        int j = tid + k*256;
        yn[ybase+j] = __float2bfloat16(yg[k] * rn * norm_w[j]);
    }
}

// ---------------- launch ----------------
extern "C" void kernel_launch(void* const* d_in, const int* in_sizes, int n_in,
                              void* d_out, int out_size, void* d_ws, size_t ws_size,
                              hipStream_t stream) {
    const float* u      = (const float*)d_in[0];
    const float* w_in   = (const float*)d_in[1];
    const float* conv_w = (const float*)d_in[2];
    const float* conv_b = (const float*)d_in[3];
    const float* norm_w = (const float*)d_in[4];
    const float* w_out  = (const float*)d_in[5];
    (void)in_sizes; (void)n_in; (void)out_size;

    char* ws = (char*)d_ws;
    const size_t nWin  = (size_t)D_IN_PROJ * D_MODEL;
    const size_t nWout = (size_t)D_MODEL * D_INNER;
    __hip_bfloat16* win_bf  = (__hip_bfloat16*)ws;
    __hip_bfloat16* wout_bf = (__hip_bfloat16*)(ws + nWin*2);
    const size_t wbytes = nWin*2 + nWout*2;
    char* arena = ws + wbytes;

    const size_t perRow = 10624;
    int CB = 32;
    while (CB > 1 && wbytes + perRow*(size_t)CB*1024 > ws_size) CB >>= 1;
    const int nchunks = 32 / CB;
    const size_t R = (size_t)CB * 1024;

    __hip_bfloat16* segA = (__hip_bfloat16*)arena;                 // u_bf, then yf
    char* pC = arena + R*3072;
    char* pD = pC + R*3584;
    char* pE = pD + R*384;
    __hip_bfloat16* xbc_bf  = (__hip_bfloat16*)pC;                 // then yr
    __hip_bfloat16* yr_bf   = (__hip_bfloat16*)pC;
    float*          dt_f32  = (float*)pD;
    __hip_bfloat16* conv_bf = (__hip_bfloat16*)pE;                 // then yn
    __hip_bfloat16* yn_bf   = (__hip_bfloat16*)pE;
    __hip_bfloat16* u_bf    = segA;
    __hip_bfloat16* yf_bf   = segA;

    cvt_kernel<<<(int)((nWin/4 + 255)/256), 256, 0, stream>>>(w_in, win_bf, (int)(nWin/4));
    cvt_kernel<<<(int)((nWout/4 + 255)/256), 256, 0, stream>>>(w_out, wout_bf, (int)(nWout/4));

    for (int c = 0; c < nchunks; ++c) {
        const float* u_c = u + (size_t)c * R * D_MODEL;
        __hip_bfloat16* z_bf = (__hip_bfloat16*)((char*)d_out + (size_t)c * R * 3072);
        float* out_c = (float*)d_out + (size_t)c * R * D_MODEL;

        const size_t nUc4 = R * D_MODEL / 4;
        cvt_kernel<<<(int)((nUc4 + 255)/256), 256, 0, stream>>>(u_c, u_bf, (int)nUc4);

        gemm_bt<1><<<dim3((int)(R/128), (D_IN_PROJ + 127)/128), 256, 0, stream>>>(
            u_bf, win_bf, nullptr, z_bf, xbc_bf, dt_f32, (int)R, D_IN_PROJ, D_MODEL);

        conv_kernel<<<(int)((R*CONV_DIM)/256), 256, 0, stream>>>(xbc_bf, conv_w, conv_b, conv_bf);

        scan_ssd<<<dim3(CB, NH, 2), 256, 0, stream>>>(
            (const __bf16*)conv_bf, dt_f32, (__bf16*)yf_bf, (__bf16*)yr_bf);

        gate_kernel<<<(int)R, 256, 0, stream>>>(yf_bf, yr_bf, z_bf, norm_w, yn_bf);

        gemm_bt<0><<<dim3((int)(R/128), D_MODEL/128), 256, 0, stream>>>(
            yn_bf, wout_bf, out_c, nullptr, nullptr, nullptr, (int)R, D_MODEL, D_INNER);
    }
}